// Round 2
// baseline (259.335 us; speedup 1.0000x reference)
//
#include <hip/hip_runtime.h>
#include <hip/hip_bf16.h>

// ---------------------------------------------------------------------------
// Causal MHA. B=2, S=2048, D=1024, H=16, Dh=64. Inputs fp32, output fp32.
// Internal bf16 MFMA.
// Memory plan (ws 24 MB, d_out 16 MB):
//   d_out[0:8MB]   Q   (B,H,S,Dh) bf16     d_out[8:16MB]  xb (4096,1024) bf16
//   ws[0:8MB]      K   (B,H,S,Dh) bf16 (dead after attn -> Wo-bf16)
//   ws[8:16MB]     VT  (B,H,Dh,S) bf16
//   ws[16:24MB]    Wq/Wk/Wv bf16 (6MB) + rope table (512KB) during qkv,
//                  then ATT (B,S,D) bf16 overwrites
// R15: attn VALU diet. r14 post-mortem: attn 75us, VALUBusy 40% vs MfmaUtil
// 9% -> softmax VALU chain dominates (~600 instrs/wave-iter). Changes:
//   (a) f2bf bit-twiddle -> native __bf16 casts (v_cvt_pk_bf16_f32, 1 op)
//   (b) row-max/row-sum serial chains -> depth-5 trees
//   (c) defer-max (THR=8): skip ot*=alpha rescale when max didn't grow
//   (d) 2x-unrolled ping-pong K buffers (kills 32 v_mov rotate/iter)
// GEMMs unchanged from R14 (LDS-staged 128x128, global_load_lds).
// ---------------------------------------------------------------------------

typedef __bf16 bf16x8 __attribute__((ext_vector_type(8)));
typedef __bf16 bf16x4 __attribute__((ext_vector_type(4)));
typedef float floatx4 __attribute__((ext_vector_type(4)));
typedef float floatx16 __attribute__((ext_vector_type(16)));

#define MFMA16(A, B, C) __builtin_amdgcn_mfma_f32_16x16x32_bf16((A), (B), (C), 0, 0, 0)
#define MFMA32(A, B, C) __builtin_amdgcn_mfma_f32_32x32x16_bf16((A), (B), (C), 0, 0, 0)

#define S_LEN 2048
#define D_MODEL 1024
#define NHEAD 16
#define DHEAD 64
#define NTOK 4096
#define NEG_SENTINEL (-1.0e30f)

__device__ __forceinline__ short b16(float f) {
  __bf16 h = (__bf16)f;
  union { __bf16 b; short s; } u; u.b = h;
  return u.s;
}
__device__ __forceinline__ bf16x8 ld_frag(const short* p) {
  return *(const bf16x8*)p;
}
// async global->LDS, 16B per lane; LDS dest = wave-uniform base + lane*16.
__device__ __forceinline__ void gl2lds16(const short* g, short* l) {
  __builtin_amdgcn_global_load_lds(
      (const __attribute__((address_space(1))) unsigned int*)g,
      (__attribute__((address_space(3))) unsigned int*)l, 16, 0, 0);
}

// ---------------------------------------------------------------------------
// One-time RoPE table: tab[s*32+p] = (cos, sin)(s * 10000^(-p/32)).
// ---------------------------------------------------------------------------
__global__ __launch_bounds__(256) void rope_tab_kernel(float2* __restrict__ tab) {
  int i = blockIdx.x * 256 + threadIdx.x;  // 65536 = 2048*32
  int s = i >> 5, p = i & 31;
  float inv_freq = __expf(-0.28782313662425575f * (float)p);
  float ang = (float)s * inv_freq;
  float sn, c;
  sincosf(ang, &sn, &c);  // accurate; one-time cost
  tab[i] = make_float2(c, sn);
}

// ---------------------------------------------------------------------------
__global__ __launch_bounds__(256) void cvt4_kernel(
    const float* __restrict__ x, const float* __restrict__ wq,
    const float* __restrict__ wk, const float* __restrict__ wv,
    short* __restrict__ xb, short* __restrict__ wqb,
    short* __restrict__ wkb, short* __restrict__ wvb) {
  const int y = blockIdx.y;
  const float* src = (y == 0) ? x : (y == 1) ? wq : (y == 2) ? wk : wv;
  short* dst = (y == 0) ? xb : (y == 1) ? wqb : (y == 2) ? wkb : wvb;
  const int n4 = ((y == 0) ? NTOK * D_MODEL : D_MODEL * D_MODEL) >> 2;
  for (int i = blockIdx.x * 256 + threadIdx.x; i < n4; i += gridDim.x * 256) {
    float4 v = ((const float4*)src)[i];
    short4 o;
    o.x = b16(v.x); o.y = b16(v.y); o.z = b16(v.z); o.w = b16(v.w);
    ((short4*)dst)[i] = o;
  }
}
__global__ __launch_bounds__(256) void cvt1_kernel(
    const float* __restrict__ src, short* __restrict__ dst, int n4) {
  for (int i = blockIdx.x * 256 + threadIdx.x; i < n4; i += gridDim.x * 256) {
    float4 v = ((const float4*)src)[i];
    short4 o;
    o.x = b16(v.x); o.y = b16(v.y); o.z = b16(v.z); o.w = b16(v.w);
    ((short4*)dst)[i] = o;
  }
}

// ---------------------------------------------------------------------------
// QKV + RoPE: LDS-staged 128x128 tile per block (m97 structure), unchanged
// from R14 except native bf16 casts in the epilogue.
// ---------------------------------------------------------------------------
__global__ __launch_bounds__(256) void qkv_rope_kernel(
    const short* __restrict__ xb,
    const short* __restrict__ Wqb, const short* __restrict__ Wkb,
    const short* __restrict__ Wvb,
    const float2* __restrict__ ropetab,
    short* __restrict__ qws, short* __restrict__ kws, short* __restrict__ vtws) {
  __shared__ __align__(16) short SM[4 * 64 * 72];  // 36KB: staging, then epilogue
  short* As = SM;              // [128][32] bf16, row-major (64B rows)
  short* Bs = SM + 128 * 32;

  const int tid = threadIdx.x;
  const int lane = tid & 63;
  const int wv = tid >> 6;
  const int col = lane & 15, quad = lane >> 4;
  const int wr = wv >> 1, wc = wv & 1;
  const int gemm = blockIdx.y;
  const int bm = blockIdx.x >> 3;
  const int bn = blockIdx.x & 7;
  const short* W = (gemm == 0) ? Wqb : (gemm == 1) ? Wkb : Wvb;

  const int srow = wv * 16 + (lane >> 2);
  const int skoff = (lane & 3) * 8;
  const short* gA0 = xb + (size_t)(bm * 128 + srow) * D_MODEL + skoff;
  const short* gA1 = gA0 + (size_t)64 * D_MODEL;
  const short* gB0 = W + (size_t)(bn * 128 + srow) * D_MODEL + skoff;
  const short* gB1 = gB0 + (size_t)64 * D_MODEL;
  short* lA0 = As + (wv * 16) * 32;          // wave-uniform LDS bases
  short* lA1 = lA0 + 64 * 32;
  short* lB0 = Bs + (wv * 16) * 32;
  short* lB1 = lB0 + 64 * 32;

  floatx4 acc[4][4];
#pragma unroll
  for (int i = 0; i < 4; ++i)
#pragma unroll
    for (int j = 0; j < 4; ++j) acc[i][j] = (floatx4){0.f, 0.f, 0.f, 0.f};

  for (int k0 = 0; k0 < D_MODEL; k0 += 32) {
    __syncthreads();
    gl2lds16(gA0 + k0, lA0);
    gl2lds16(gA1 + k0, lA1);
    gl2lds16(gB0 + k0, lB0);
    gl2lds16(gB1 + k0, lB1);
    __syncthreads();
    bf16x8 a[4], b[4];
#pragma unroll
    for (int mt = 0; mt < 4; ++mt)
      a[mt] = ld_frag(&As[(wr * 64 + mt * 16 + col) * 32 + quad * 8]);
#pragma unroll
    for (int nt = 0; nt < 4; ++nt)
      b[nt] = ld_frag(&Bs[(wc * 64 + nt * 16 + col) * 32 + quad * 8]);
#pragma unroll
    for (int mt = 0; mt < 4; ++mt)
#pragma unroll
      for (int nt = 0; nt < 4; ++nt)
        acc[mt][nt] = MFMA16(a[mt], b[nt], acc[mt][nt]);
  }
  __syncthreads();  // staging region about to be reused as epilogue buffer

  // ---- epilogue (per-wave 64x64 tile) -------------------------------------
  const int tm = bm * 2 + wr;   // 0..63
  const int tn = bn * 2 + wc;   // 0..15 (= head)
  short* Ep = &SM[wv * 64 * 72];
  const int mbase = tm * 64;
  const int bb = mbase >> 11;
  const int s0 = mbase & (S_LEN - 1);

  if (gemm == 2) {
#pragma unroll
    for (int mt = 0; mt < 4; ++mt)
#pragma unroll
      for (int nt = 0; nt < 4; ++nt) {
        int nl = nt * 16 + col;
#pragma unroll
        for (int r = 0; r < 4; ++r)
          Ep[nl * 72 + mt * 16 + quad * 4 + r] = b16(acc[mt][nt][r]);
      }
    int4* d4 = (int4*)(vtws + ((size_t)(bb * NHEAD + tn) * DHEAD + lane) * S_LEN + s0);
    const int4* src = (const int4*)&Ep[lane * 72];
#pragma unroll
    for (int i = 0; i < 8; ++i) d4[i] = src[i];
  } else {
    short* outp = (gemm == 0) ? qws : kws;
    const float qscale = (gemm == 0) ? 0.125f : 1.0f;
#pragma unroll
    for (int nt = 0; nt < 4; ++nt) {
      int nl = nt * 16 + col;
      const float2* tp = ropetab + (nl >> 1);
#pragma unroll
      for (int mt = 0; mt < 4; ++mt)
#pragma unroll
        for (int r = 0; r < 4; ++r) {
          int ml = mt * 16 + quad * 4 + r;
          float2 cs = tp[(size_t)(s0 + ml) * 32];
          float val = acc[mt][nt][r];
          float partner = __shfl_xor(val, 1);
          float o = ((nl & 1) == 0) ? (val * cs.x - partner * cs.y)
                                    : (partner * cs.y + val * cs.x);
          Ep[ml * 72 + nl] = b16(o * qscale);
        }
    }
    int4* d4 = (int4*)(outp + ((size_t)(bb * NHEAD + tn) * S_LEN + s0 + lane) * DHEAD);
    const int4* src = (const int4*)&Ep[lane * 72];
#pragma unroll
    for (int i = 0; i < 8; ++i) d4[i] = src[i];
  }
}

// ---------------------------------------------------------------------------
// Split-K flash attention. R15: VALU diet (native bf16 casts, tree
// reductions, defer-max THR=8, ping-pong K buffers without rotate).
// grid 2048 x 256; block = 4 waves per (b,h,32-q-tile); wave w handles
// key-tiles it = w, w+4, ...
// ---------------------------------------------------------------------------
__global__ __launch_bounds__(256) void attn_kernel(
    const short* __restrict__ qws, const short* __restrict__ kws,
    const short* __restrict__ vtws, short* __restrict__ att) {
  const int tid = threadIdx.x;
  const int wv = tid >> 6;
  const int lane = tid & 63;
  const int half = lane >> 5, l31 = lane & 31;
  const int bh = blockIdx.x & 31;          // consecutive blocks -> different
  const int b = bh >> 4, h = bh & 15;      // (b,h): same (b,h) lands on the
  const int qt = 63 - (blockIdx.x >> 5);   // same XCD (round-robin heuristic)
  const int q0 = qt * 32;

  __shared__ __align__(16) short P[4][32][72];   // per-wave P buffers
  __shared__ float ml[2][4][32];   // [0]=m, [1]=l  per wave per q
  __shared__ float Obuf[64][33];   // merged O^T (d, q) fp32

  const short* qbase = qws + (size_t)(b * NHEAD + h) * S_LEN * DHEAD;
  const short* kbase = kws + (size_t)(b * NHEAD + h) * S_LEN * DHEAD;
  const short* vbase = vtws + (size_t)(b * NHEAD + h) * DHEAD * S_LEN;

  bf16x8 qf[4];
#pragma unroll
  for (int kc = 0; kc < 4; ++kc)
    qf[kc] = ld_frag(qbase + (size_t)(q0 + l31) * DHEAD + kc * 16 + half * 8);

  float m_i = NEG_SENTINEL, l_i = 0.f;
  floatx16 ot[2] = {};  // O^T: d = dt*32+(rg&3)+8*(rg>>2)+4*half, q = l31

  const int nit = (q0 + 32 + 63) >> 6;  // total 64-key tiles

  bf16x8 kfA[2][4], kfB[2][4];  // K ping-pong buffers
  auto loadK = [&](bf16x8 (&dst)[2][4], int tkt) {
#pragma unroll
    for (int s = 0; s < 2; ++s) {
      if (tkt + s * 32 <= q0 + 31) {  // wave-uniform validity
        const short* kr = kbase + (size_t)(tkt + s * 32 + l31) * DHEAD + half * 8;
#pragma unroll
        for (int kc = 0; kc < 4; ++kc) dst[s][kc] = ld_frag(kr + kc * 16);
      }
    }
  };

  // one 64-key tile; cur holds this tile's K, next gets the prefetch
  auto body = [&](bf16x8 (&cur)[2][4], bf16x8 (&nxt)[2][4], int myit) {
    const int kt = myit * 64;
    // --- V loads first: no deps, latency overlaps the whole softmax chain
    bf16x8 vf[4][2];
#pragma unroll
    for (int kc = 0; kc < 4; ++kc)
#pragma unroll
      for (int dt = 0; dt < 2; ++dt)
        vf[kc][dt] = ld_frag(vbase + (size_t)(dt * 32 + l31) * S_LEN + kt + kc * 16 + half * 8);
    // --- scores from the prefetched K registers
    floatx16 sc[2];
#pragma unroll
    for (int s = 0; s < 2; ++s) {
      if (kt + s * 32 <= q0 + 31) {
        floatx16 a = {};
#pragma unroll
        for (int kc = 0; kc < 4; ++kc) a = MFMA32(cur[s][kc], qf[kc], a);
        sc[s] = a;
      } else {
#pragma unroll
        for (int rg = 0; rg < 16; ++rg) sc[s][rg] = NEG_SENTINEL;
      }
    }
    // --- prefetch next iteration's K (overlaps softmax + PV)
    if (myit + 4 < nit) loadK(nxt, (myit + 4) * 64);

    // --- causal mask (wave-uniform skip for full tiles)
    if (kt + 63 > q0) {
      const int lim = q0 + l31 - kt;  // key-rel <= lim is valid
#pragma unroll
      for (int s = 0; s < 2; ++s)
#pragma unroll
        for (int rg = 0; rg < 16; ++rg) {
          int rel = s * 32 + (rg & 3) + 8 * (rg >> 2) + 4 * half;
          if (rel > lim) sc[s][rg] = NEG_SENTINEL;
        }
    }
    // --- row max: depth-5 tree + 1 shuffle
    float t[16];
#pragma unroll
    for (int i = 0; i < 16; ++i) t[i] = fmaxf(sc[0][i], sc[1][i]);
#pragma unroll
    for (int off = 8; off; off >>= 1)
#pragma unroll
      for (int i = 0; i < off; ++i) t[i] = fmaxf(t[i], t[i + off]);
    float rm = fmaxf(t[0], __shfl_xor(t[0], 32));

    // --- defer-max: rescale only when the running max actually grew
    if (!__all(rm <= m_i + 8.0f)) {
      float mnew = fmaxf(m_i, rm);
      float alpha = __expf(m_i - mnew);
      m_i = mnew;
      l_i *= alpha;
#pragma unroll
      for (int dt = 0; dt < 2; ++dt)
#pragma unroll
        for (int rg = 0; rg < 16; ++rg) ot[dt][rg] *= alpha;
    }

    // --- P = exp(S - m), packed via native cvt (1 op/elem), 8B LDS stores
    float rsp[8];
#pragma unroll
    for (int s = 0; s < 2; ++s)
#pragma unroll
      for (int g = 0; g < 4; ++g) {
        float p0 = __expf(sc[s][4 * g + 0] - m_i);
        float p1 = __expf(sc[s][4 * g + 1] - m_i);
        float p2 = __expf(sc[s][4 * g + 2] - m_i);
        float p3 = __expf(sc[s][4 * g + 3] - m_i);
        rsp[s * 4 + g] = (p0 + p1) + (p2 + p3);
        bf16x4 w;
        w[0] = (__bf16)p0; w[1] = (__bf16)p1; w[2] = (__bf16)p2; w[3] = (__bf16)p3;
        *(bf16x4*)&P[wv][l31][s * 32 + 8 * g + 4 * half] = w;
      }
    float rs = ((rsp[0] + rsp[1]) + (rsp[2] + rsp[3])) +
               ((rsp[4] + rsp[5]) + (rsp[6] + rsp[7]));
    rs += __shfl_xor(rs, 32);
    l_i += rs;

    // --- PV from prefetched V registers (intra-wave LDS round-trip for P)
#pragma unroll
    for (int kc = 0; kc < 4; ++kc) {
      bf16x8 pb = ld_frag(&P[wv][l31][kc * 16 + half * 8]);
#pragma unroll
      for (int dt = 0; dt < 2; ++dt)
        ot[dt] = MFMA32(vf[kc][dt], pb, ot[dt]);
    }
  };

  int it = wv;
  if (it < nit) {
    loadK(kfA, it * 64);  // prologue
    while (true) {
      body(kfA, kfB, it);
      it += 4; if (it >= nit) break;
      body(kfB, kfA, it);
      it += 4; if (it >= nit) break;
    }
  }

  // ---- block merge ------------------------------------------------------
  ml[0][wv][l31] = m_i;
  ml[1][wv][l31] = l_i;
  __syncthreads();
  float m0 = ml[0][0][l31], m1 = ml[0][1][l31];
  float m2 = ml[0][2][l31], m3 = ml[0][3][l31];
  float mtot = fmaxf(fmaxf(m0, m1), fmaxf(m2, m3));
  float sw = __expf(m_i - mtot);  // idle wave: 0

  if (wv == 0) {
#pragma unroll
    for (int dt = 0; dt < 2; ++dt)
#pragma unroll
      for (int rg = 0; rg < 16; ++rg) {
        int d = dt * 32 + (rg & 3) + 8 * (rg >> 2) + 4 * half;
        Obuf[d][l31] = ot[dt][rg] * sw;
      }
  }
  __syncthreads();
#pragma unroll
  for (int w = 1; w < 4; ++w) {
    if (wv == w) {
#pragma unroll
      for (int dt = 0; dt < 2; ++dt)
#pragma unroll
        for (int rg = 0; rg < 16; ++rg) {
          int d = dt * 32 + (rg & 3) + 8 * (rg >> 2) + 4 * half;
          Obuf[d][l31] += ot[dt][rg] * sw;
        }
    }
    __syncthreads();
  }

  // ---- final normalize + coalesced store (128B per q-row) ---------------
  const int q = tid >> 3;            // 0..31
  const int d0 = (tid & 7) * 8;      // 0,8,..,56
  float mm0 = ml[0][0][q], mm1 = ml[0][1][q], mm2 = ml[0][2][q], mm3 = ml[0][3][q];
  float mt2 = fmaxf(fmaxf(mm0, mm1), fmaxf(mm2, mm3));
  float lt = ml[1][0][q] * __expf(mm0 - mt2) + ml[1][1][q] * __expf(mm1 - mt2) +
             ml[1][2][q] * __expf(mm2 - mt2) + ml[1][3][q] * __expf(mm3 - mt2);
  float inv = 1.0f / lt;  // lt >= 1
  union { bf16x8 h; int4 i4; } cv;
#pragma unroll
  for (int i = 0; i < 8; ++i) cv.h[i] = (__bf16)(Obuf[d0 + i][q] * inv);
  int4* dst = (int4*)(att + (size_t)(b * S_LEN + q0 + q) * D_MODEL + h * DHEAD + d0);
  *dst = cv.i4;
}

// ---------------------------------------------------------------------------
// Output projection: LDS-staged 128x128 tile (unchanged from R14).
// out = att (bf16) @ Wo^T (bf16) -> fp32. grid 256 x 256.
// ---------------------------------------------------------------------------
__global__ __launch_bounds__(256) void out_gemm_kernel(
    const short* __restrict__ att, const short* __restrict__ Wob,
    float* __restrict__ out) {
  __shared__ __align__(16) short As[128 * 32];
  __shared__ __align__(16) short Bs[128 * 32];

  const int tid = threadIdx.x;
  const int lane = tid & 63;
  const int wv = tid >> 6;
  const int col = lane & 15, quad = lane >> 4;
  const int wr = wv >> 1, wc = wv & 1;
  const int bm = blockIdx.x >> 3;
  const int bn = blockIdx.x & 7;

  const int srow = wv * 16 + (lane >> 2);
  const int skoff = (lane & 3) * 8;
  const short* gA0 = att + (size_t)(bm * 128 + srow) * D_MODEL + skoff;
  const short* gA1 = gA0 + (size_t)64 * D_MODEL;
  const short* gB0 = Wob + (size_t)(bn * 128 + srow) * D_MODEL + skoff;
  const short* gB1 = gB0 + (size_t)64 * D_MODEL;
  short* lA0 = As + (wv * 16) * 32;
  short* lA1 = lA0 + 64 * 32;
  short* lB0 = Bs + (wv * 16) * 32;
  short* lB1 = lB0 + 64 * 32;

  floatx4 acc[4][4];
#pragma unroll
  for (int i = 0; i < 4; ++i)
#pragma unroll
    for (int j = 0; j < 4; ++j) acc[i][j] = (floatx4){0.f, 0.f, 0.f, 0.f};

  for (int k0 = 0; k0 < D_MODEL; k0 += 32) {
    __syncthreads();
    gl2lds16(gA0 + k0, lA0);
    gl2lds16(gA1 + k0, lA1);
    gl2lds16(gB0 + k0, lB0);
    gl2lds16(gB1 + k0, lB1);
    __syncthreads();
    bf16x8 a[4], b[4];
#pragma unroll
    for (int mt = 0; mt < 4; ++mt)
      a[mt] = ld_frag(&As[(wr * 64 + mt * 16 + col) * 32 + quad * 8]);
#pragma unroll
    for (int nt = 0; nt < 4; ++nt)
      b[nt] = ld_frag(&Bs[(wc * 64 + nt * 16 + col) * 32 + quad * 8]);
#pragma unroll
    for (int mt = 0; mt < 4; ++mt)
#pragma unroll
      for (int nt = 0; nt < 4; ++nt)
        acc[mt][nt] = MFMA16(a[mt], b[nt], acc[mt][nt]);
  }

  const int tm = bm * 2 + wr;
  const int tn = bn * 2 + wc;
#pragma unroll
  for (int mt = 0; mt < 4; ++mt)
#pragma unroll
    for (int nt = 0; nt < 4; ++nt) {
      int n = tn * 64 + nt * 16 + col;
#pragma unroll
      for (int r = 0; r < 4; ++r) {
        int m = tm * 64 + mt * 16 + quad * 4 + r;
        out[(size_t)m * D_MODEL + n] = acc[mt][nt][r];
      }
    }
}

// ---------------------------------------------------------------------------
extern "C" void kernel_launch(void* const* d_in, const int* in_sizes, int n_in,
                              void* d_out, int out_size, void* d_ws, size_t ws_size,
                              hipStream_t stream) {
  const float* x  = (const float*)d_in[0];
  const float* Wq = (const float*)d_in[2];
  const float* Wk = (const float*)d_in[3];
  const float* Wv = (const float*)d_in[4];
  const float* Wo = (const float*)d_in[5];
  float* out = (float*)d_out;

  const size_t TENS = (size_t)NTOK * D_MODEL;
  const size_t WELEM = (size_t)D_MODEL * D_MODEL;

  short* qws  = (short*)d_out;
  short* xb   = (short*)d_out + TENS;
  short* kws  = (short*)d_ws;
  short* vtws = kws + TENS;
  short* attws = vtws + TENS;
  short* wqb = attws;
  short* wkb = wqb + WELEM;
  short* wvb = wkb + WELEM;
  float2* ropetab = (float2*)(wvb + WELEM);
  short* wob = kws;

  rope_tab_kernel<<<dim3(256), 256, 0, stream>>>(ropetab);
  cvt4_kernel<<<dim3(256, 4), 256, 0, stream>>>(x, Wq, Wk, Wv, xb, wqb, wkb, wvb);
  qkv_rope_kernel<<<dim3(256, 3), 256, 0, stream>>>(xb, wqb, wkb, wvb, ropetab, qws, kws, vtws);
  attn_kernel<<<dim3(2048), 256, 0, stream>>>(qws, kws, vtws, attws);
  cvt1_kernel<<<dim3(256), 256, 0, stream>>>(Wo, wob, (int)(WELEM >> 2));
  out_gemm_kernel<<<dim3(256), 256, 0, stream>>>(attws, wob, out);
}

// Round 3
// 238.010 us; speedup vs baseline: 1.0896x; 1.0896x over previous
//
#include <hip/hip_runtime.h>
#include <hip/hip_bf16.h>

// ---------------------------------------------------------------------------
// Causal MHA. B=2, S=2048, D=1024, H=16, Dh=64. Inputs fp32, output fp32.
// Internal bf16 MFMA.
// Memory plan (ws 24 MB, d_out 16 MB):
//   d_out[0:8MB]   Q   (B,H,S,Dh) bf16     d_out[8:16MB]  xb (4096,1024) bf16
//   ws[0:8MB]      K   (B,H,S,Dh) bf16 (dead after attn -> Wo-bf16)
//   ws[8:16MB]     VT  (B,H,Dh,S) bf16
//   ws[16:24MB]    Wq/Wk/Wv bf16 (6MB) + rope table (512KB) during qkv,
//                  then ATT (B,S,D) bf16 overwrites
// R16: r15 post-mortem — VALU diet worked (VALUBusy 40->29%) but the 2x
// body unroll doubled live ranges (VGPR 116->160), occupancy halved
// (20->10.6%), net regression 75->96us. R16 = R14's single-body loop
// (explicit K rotate, ~116 VGPR) + the cheap VALU cuts (native bf16 casts,
// depth-5 trees, defer-max) + NEW log2-domain softmax: log2(e) folded into
// the Q scale so every __expf becomes a single v_exp_f32 (exp2).
// GEMMs unchanged from R14 (LDS-staged 128x128, global_load_lds).
// ---------------------------------------------------------------------------

typedef __bf16 bf16x8 __attribute__((ext_vector_type(8)));
typedef __bf16 bf16x4 __attribute__((ext_vector_type(4)));
typedef float floatx4 __attribute__((ext_vector_type(4)));
typedef float floatx16 __attribute__((ext_vector_type(16)));

#define MFMA16(A, B, C) __builtin_amdgcn_mfma_f32_16x16x32_bf16((A), (B), (C), 0, 0, 0)
#define MFMA32(A, B, C) __builtin_amdgcn_mfma_f32_32x32x16_bf16((A), (B), (C), 0, 0, 0)

#define S_LEN 2048
#define D_MODEL 1024
#define NHEAD 16
#define DHEAD 64
#define NTOK 4096
#define NEG_SENTINEL (-1.0e30f)
// 0.125 (1/sqrt(Dh)) * log2(e): scores leave QKV pre-scaled for exp2-softmax
#define QSCALE_LOG2E 0.18033688011112042f

__device__ __forceinline__ short b16(float f) {
  __bf16 h = (__bf16)f;
  union { __bf16 b; short s; } u; u.b = h;
  return u.s;
}
__device__ __forceinline__ bf16x8 ld_frag(const short* p) {
  return *(const bf16x8*)p;
}
// async global->LDS, 16B per lane; LDS dest = wave-uniform base + lane*16.
__device__ __forceinline__ void gl2lds16(const short* g, short* l) {
  __builtin_amdgcn_global_load_lds(
      (const __attribute__((address_space(1))) unsigned int*)g,
      (__attribute__((address_space(3))) unsigned int*)l, 16, 0, 0);
}

// ---------------------------------------------------------------------------
// One-time RoPE table: tab[s*32+p] = (cos, sin)(s * 10000^(-p/32)).
// ---------------------------------------------------------------------------
__global__ __launch_bounds__(256) void rope_tab_kernel(float2* __restrict__ tab) {
  int i = blockIdx.x * 256 + threadIdx.x;  // 65536 = 2048*32
  int s = i >> 5, p = i & 31;
  float inv_freq = __expf(-0.28782313662425575f * (float)p);
  float ang = (float)s * inv_freq;
  float sn, c;
  sincosf(ang, &sn, &c);  // accurate; one-time cost
  tab[i] = make_float2(c, sn);
}

// ---------------------------------------------------------------------------
__global__ __launch_bounds__(256) void cvt4_kernel(
    const float* __restrict__ x, const float* __restrict__ wq,
    const float* __restrict__ wk, const float* __restrict__ wv,
    short* __restrict__ xb, short* __restrict__ wqb,
    short* __restrict__ wkb, short* __restrict__ wvb) {
  const int y = blockIdx.y;
  const float* src = (y == 0) ? x : (y == 1) ? wq : (y == 2) ? wk : wv;
  short* dst = (y == 0) ? xb : (y == 1) ? wqb : (y == 2) ? wkb : wvb;
  const int n4 = ((y == 0) ? NTOK * D_MODEL : D_MODEL * D_MODEL) >> 2;
  for (int i = blockIdx.x * 256 + threadIdx.x; i < n4; i += gridDim.x * 256) {
    float4 v = ((const float4*)src)[i];
    short4 o;
    o.x = b16(v.x); o.y = b16(v.y); o.z = b16(v.z); o.w = b16(v.w);
    ((short4*)dst)[i] = o;
  }
}
__global__ __launch_bounds__(256) void cvt1_kernel(
    const float* __restrict__ src, short* __restrict__ dst, int n4) {
  for (int i = blockIdx.x * 256 + threadIdx.x; i < n4; i += gridDim.x * 256) {
    float4 v = ((const float4*)src)[i];
    short4 o;
    o.x = b16(v.x); o.y = b16(v.y); o.z = b16(v.z); o.w = b16(v.w);
    ((short4*)dst)[i] = o;
  }
}

// ---------------------------------------------------------------------------
// QKV + RoPE: LDS-staged 128x128 tile per block (m97 structure).
// Q epilogue scale now folds log2(e) for the exp2-domain softmax.
// ---------------------------------------------------------------------------
__global__ __launch_bounds__(256) void qkv_rope_kernel(
    const short* __restrict__ xb,
    const short* __restrict__ Wqb, const short* __restrict__ Wkb,
    const short* __restrict__ Wvb,
    const float2* __restrict__ ropetab,
    short* __restrict__ qws, short* __restrict__ kws, short* __restrict__ vtws) {
  __shared__ __align__(16) short SM[4 * 64 * 72];  // 36KB: staging, then epilogue
  short* As = SM;              // [128][32] bf16, row-major (64B rows)
  short* Bs = SM + 128 * 32;

  const int tid = threadIdx.x;
  const int lane = tid & 63;
  const int wv = tid >> 6;
  const int col = lane & 15, quad = lane >> 4;
  const int wr = wv >> 1, wc = wv & 1;
  const int gemm = blockIdx.y;
  const int bm = blockIdx.x >> 3;
  const int bn = blockIdx.x & 7;
  const short* W = (gemm == 0) ? Wqb : (gemm == 1) ? Wkb : Wvb;

  const int srow = wv * 16 + (lane >> 2);
  const int skoff = (lane & 3) * 8;
  const short* gA0 = xb + (size_t)(bm * 128 + srow) * D_MODEL + skoff;
  const short* gA1 = gA0 + (size_t)64 * D_MODEL;
  const short* gB0 = W + (size_t)(bn * 128 + srow) * D_MODEL + skoff;
  const short* gB1 = gB0 + (size_t)64 * D_MODEL;
  short* lA0 = As + (wv * 16) * 32;          // wave-uniform LDS bases
  short* lA1 = lA0 + 64 * 32;
  short* lB0 = Bs + (wv * 16) * 32;
  short* lB1 = lB0 + 64 * 32;

  floatx4 acc[4][4];
#pragma unroll
  for (int i = 0; i < 4; ++i)
#pragma unroll
    for (int j = 0; j < 4; ++j) acc[i][j] = (floatx4){0.f, 0.f, 0.f, 0.f};

  for (int k0 = 0; k0 < D_MODEL; k0 += 32) {
    __syncthreads();
    gl2lds16(gA0 + k0, lA0);
    gl2lds16(gA1 + k0, lA1);
    gl2lds16(gB0 + k0, lB0);
    gl2lds16(gB1 + k0, lB1);
    __syncthreads();
    bf16x8 a[4], b[4];
#pragma unroll
    for (int mt = 0; mt < 4; ++mt)
      a[mt] = ld_frag(&As[(wr * 64 + mt * 16 + col) * 32 + quad * 8]);
#pragma unroll
    for (int nt = 0; nt < 4; ++nt)
      b[nt] = ld_frag(&Bs[(wc * 64 + nt * 16 + col) * 32 + quad * 8]);
#pragma unroll
    for (int mt = 0; mt < 4; ++mt)
#pragma unroll
      for (int nt = 0; nt < 4; ++nt)
        acc[mt][nt] = MFMA16(a[mt], b[nt], acc[mt][nt]);
  }
  __syncthreads();  // staging region about to be reused as epilogue buffer

  // ---- epilogue (per-wave 64x64 tile) -------------------------------------
  const int tm = bm * 2 + wr;   // 0..63
  const int tn = bn * 2 + wc;   // 0..15 (= head)
  short* Ep = &SM[wv * 64 * 72];
  const int mbase = tm * 64;
  const int bb = mbase >> 11;
  const int s0 = mbase & (S_LEN - 1);

  if (gemm == 2) {
#pragma unroll
    for (int mt = 0; mt < 4; ++mt)
#pragma unroll
      for (int nt = 0; nt < 4; ++nt) {
        int nl = nt * 16 + col;
#pragma unroll
        for (int r = 0; r < 4; ++r)
          Ep[nl * 72 + mt * 16 + quad * 4 + r] = b16(acc[mt][nt][r]);
      }
    int4* d4 = (int4*)(vtws + ((size_t)(bb * NHEAD + tn) * DHEAD + lane) * S_LEN + s0);
    const int4* src = (const int4*)&Ep[lane * 72];
#pragma unroll
    for (int i = 0; i < 8; ++i) d4[i] = src[i];
  } else {
    short* outp = (gemm == 0) ? qws : kws;
    const float qscale = (gemm == 0) ? QSCALE_LOG2E : 1.0f;
#pragma unroll
    for (int nt = 0; nt < 4; ++nt) {
      int nl = nt * 16 + col;
      const float2* tp = ropetab + (nl >> 1);
#pragma unroll
      for (int mt = 0; mt < 4; ++mt)
#pragma unroll
        for (int r = 0; r < 4; ++r) {
          int ml = mt * 16 + quad * 4 + r;
          float2 cs = tp[(size_t)(s0 + ml) * 32];
          float val = acc[mt][nt][r];
          float partner = __shfl_xor(val, 1);
          float o = ((nl & 1) == 0) ? (val * cs.x - partner * cs.y)
                                    : (partner * cs.y + val * cs.x);
          Ep[ml * 72 + nl] = b16(o * qscale);
        }
    }
    int4* d4 = (int4*)(outp + ((size_t)(bb * NHEAD + tn) * S_LEN + s0 + lane) * DHEAD);
    const int4* src = (const int4*)&Ep[lane * 72];
#pragma unroll
    for (int i = 0; i < 8; ++i) d4[i] = src[i];
  }
}

// ---------------------------------------------------------------------------
// Split-K flash attention. R16: single loop body (R14 register budget),
// exp2-domain softmax (scores arrive pre-scaled by log2e), native bf16
// casts, depth-5 reductions, defer-max THR=8 (log2 domain: P <= 2^8).
// grid 2048 x 256; block = 4 waves per (b,h,32-q-tile); wave w handles
// key-tiles it = w, w+4, ...
// ---------------------------------------------------------------------------
__global__ __launch_bounds__(256) void attn_kernel(
    const short* __restrict__ qws, const short* __restrict__ kws,
    const short* __restrict__ vtws, short* __restrict__ att) {
  const int tid = threadIdx.x;
  const int wv = tid >> 6;
  const int lane = tid & 63;
  const int half = lane >> 5, l31 = lane & 31;
  const int bh = blockIdx.x & 31;          // consecutive blocks -> different
  const int b = bh >> 4, h = bh & 15;      // (b,h): same (b,h) lands on the
  const int qt = 63 - (blockIdx.x >> 5);   // same XCD (round-robin heuristic)
  const int q0 = qt * 32;

  __shared__ __align__(16) short P[4][32][72];   // per-wave P buffers
  __shared__ float ml[2][4][32];   // [0]=m, [1]=l  per wave per q
  __shared__ float Obuf[64][33];   // merged O^T (d, q) fp32

  const short* qbase = qws + (size_t)(b * NHEAD + h) * S_LEN * DHEAD;
  const short* kbase = kws + (size_t)(b * NHEAD + h) * S_LEN * DHEAD;
  const short* vbase = vtws + (size_t)(b * NHEAD + h) * DHEAD * S_LEN;

  bf16x8 qf[4];
#pragma unroll
  for (int kc = 0; kc < 4; ++kc)
    qf[kc] = ld_frag(qbase + (size_t)(q0 + l31) * DHEAD + kc * 16 + half * 8);

  float m_i = NEG_SENTINEL, l_i = 0.f;   // log2-domain running max / sum
  floatx16 ot[2] = {};  // O^T: d = dt*32+(rg&3)+8*(rg>>2)+4*half, q = l31

  const int nit = (q0 + 32 + 63) >> 6;  // total 64-key tiles

  bf16x8 kfA[2][4], kfB[2][4];  // K double buffer
  auto loadK = [&](bf16x8 (&dst)[2][4], int tkt) {
#pragma unroll
    for (int s = 0; s < 2; ++s) {
      if (tkt + s * 32 <= q0 + 31) {  // wave-uniform validity
        const short* kr = kbase + (size_t)(tkt + s * 32 + l31) * DHEAD + half * 8;
#pragma unroll
        for (int kc = 0; kc < 4; ++kc) dst[s][kc] = ld_frag(kr + kc * 16);
      }
    }
  };

  int it = wv;
  if (it < nit) loadK(kfA, it * 64);  // prologue

  for (; it < nit; it += 4) {
    const int kt = it * 64;
    // --- V loads first: no deps, latency overlaps the whole softmax chain
    bf16x8 vf[4][2];
#pragma unroll
    for (int kc = 0; kc < 4; ++kc)
#pragma unroll
      for (int dt = 0; dt < 2; ++dt)
        vf[kc][dt] = ld_frag(vbase + (size_t)(dt * 32 + l31) * S_LEN + kt + kc * 16 + half * 8);
    // --- scores from the prefetched K registers (already x log2e)
    floatx16 sc[2];
#pragma unroll
    for (int s = 0; s < 2; ++s) {
      if (kt + s * 32 <= q0 + 31) {
        floatx16 a = {};
#pragma unroll
        for (int kc = 0; kc < 4; ++kc) a = MFMA32(kfA[s][kc], qf[kc], a);
        sc[s] = a;
      } else {
#pragma unroll
        for (int rg = 0; rg < 16; ++rg) sc[s][rg] = NEG_SENTINEL;
      }
    }
    // --- prefetch next iteration's K (overlaps softmax + PV)
    const bool havenext = (it + 4 < nit);
    if (havenext) loadK(kfB, (it + 4) * 64);

    // --- causal mask (wave-uniform skip for full tiles)
    if (kt + 63 > q0) {
      const int lim = q0 + l31 - kt;  // key-rel <= lim is valid
#pragma unroll
      for (int s = 0; s < 2; ++s)
#pragma unroll
        for (int rg = 0; rg < 16; ++rg) {
          int rel = s * 32 + (rg & 3) + 8 * (rg >> 2) + 4 * half;
          if (rel > lim) sc[s][rg] = NEG_SENTINEL;
        }
    }
    // --- row max: depth-5 tree + 1 shuffle
    float t[16];
#pragma unroll
    for (int i = 0; i < 16; ++i) t[i] = fmaxf(sc[0][i], sc[1][i]);
#pragma unroll
    for (int off = 8; off; off >>= 1)
#pragma unroll
      for (int i = 0; i < off; ++i) t[i] = fmaxf(t[i], t[i + off]);
    float rm = fmaxf(t[0], __shfl_xor(t[0], 32));

    // --- defer-max: rescale only when the running max actually grew
    if (!__all(rm <= m_i + 8.0f)) {
      float mnew = fmaxf(m_i, rm);
      float alpha = exp2f(m_i - mnew);
      m_i = mnew;
      l_i *= alpha;
#pragma unroll
      for (int dt = 0; dt < 2; ++dt)
#pragma unroll
        for (int rg = 0; rg < 16; ++rg) ot[dt][rg] *= alpha;
    }

    // --- P = exp2(S - m): single v_exp_f32 per element; 8B LDS stores
    float rsp[8];
#pragma unroll
    for (int s = 0; s < 2; ++s)
#pragma unroll
      for (int g = 0; g < 4; ++g) {
        float p0 = exp2f(sc[s][4 * g + 0] - m_i);
        float p1 = exp2f(sc[s][4 * g + 1] - m_i);
        float p2 = exp2f(sc[s][4 * g + 2] - m_i);
        float p3 = exp2f(sc[s][4 * g + 3] - m_i);
        rsp[s * 4 + g] = (p0 + p1) + (p2 + p3);
        bf16x4 w;
        w[0] = (__bf16)p0; w[1] = (__bf16)p1; w[2] = (__bf16)p2; w[3] = (__bf16)p3;
        *(bf16x4*)&P[wv][l31][s * 32 + 8 * g + 4 * half] = w;
      }
    float rs = ((rsp[0] + rsp[1]) + (rsp[2] + rsp[3])) +
               ((rsp[4] + rsp[5]) + (rsp[6] + rsp[7]));
    rs += __shfl_xor(rs, 32);
    l_i += rs;

    // --- PV from prefetched V registers (intra-wave LDS round-trip for P)
#pragma unroll
    for (int kc = 0; kc < 4; ++kc) {
      bf16x8 pb = ld_frag(&P[wv][l31][kc * 16 + half * 8]);
#pragma unroll
      for (int dt = 0; dt < 2; ++dt)
        ot[dt] = MFMA32(vf[kc][dt], pb, ot[dt]);
    }
    // --- rotate K buffers (cheap v_movs; keeps single body = low VGPR)
    if (havenext) {
#pragma unroll
      for (int s = 0; s < 2; ++s)
#pragma unroll
        for (int kc = 0; kc < 4; ++kc) kfA[s][kc] = kfB[s][kc];
    }
  }

  // ---- block merge (log2 domain) ----------------------------------------
  ml[0][wv][l31] = m_i;
  ml[1][wv][l31] = l_i;
  __syncthreads();
  float m0 = ml[0][0][l31], m1 = ml[0][1][l31];
  float m2 = ml[0][2][l31], m3 = ml[0][3][l31];
  float mtot = fmaxf(fmaxf(m0, m1), fmaxf(m2, m3));
  float sw = exp2f(m_i - mtot);  // idle wave: 0

  if (wv == 0) {
#pragma unroll
    for (int dt = 0; dt < 2; ++dt)
#pragma unroll
      for (int rg = 0; rg < 16; ++rg) {
        int d = dt * 32 + (rg & 3) + 8 * (rg >> 2) + 4 * half;
        Obuf[d][l31] = ot[dt][rg] * sw;
      }
  }
  __syncthreads();
#pragma unroll
  for (int w = 1; w < 4; ++w) {
    if (wv == w) {
#pragma unroll
      for (int dt = 0; dt < 2; ++dt)
#pragma unroll
        for (int rg = 0; rg < 16; ++rg) {
          int d = dt * 32 + (rg & 3) + 8 * (rg >> 2) + 4 * half;
          Obuf[d][l31] += ot[dt][rg] * sw;
        }
    }
    __syncthreads();
  }

  // ---- final normalize + coalesced store (128B per q-row) ---------------
  const int q = tid >> 3;            // 0..31
  const int d0 = (tid & 7) * 8;      // 0,8,..,56
  float mm0 = ml[0][0][q], mm1 = ml[0][1][q], mm2 = ml[0][2][q], mm3 = ml[0][3][q];
  float mt2 = fmaxf(fmaxf(mm0, mm1), fmaxf(mm2, mm3));
  float lt = ml[1][0][q] * exp2f(mm0 - mt2) + ml[1][1][q] * exp2f(mm1 - mt2) +
             ml[1][2][q] * exp2f(mm2 - mt2) + ml[1][3][q] * exp2f(mm3 - mt2);
  float inv = 1.0f / lt;  // lt >= 1
  union { bf16x8 h; int4 i4; } cv;
#pragma unroll
  for (int i = 0; i < 8; ++i) cv.h[i] = (__bf16)(Obuf[d0 + i][q] * inv);
  int4* dst = (int4*)(att + (size_t)(b * S_LEN + q0 + q) * D_MODEL + h * DHEAD + d0);
  *dst = cv.i4;
}

// ---------------------------------------------------------------------------
// Output projection: LDS-staged 128x128 tile (unchanged from R14).
// out = att (bf16) @ Wo^T (bf16) -> fp32. grid 256 x 256.
// ---------------------------------------------------------------------------
__global__ __launch_bounds__(256) void out_gemm_kernel(
    const short* __restrict__ att, const short* __restrict__ Wob,
    float* __restrict__ out) {
  __shared__ __align__(16) short As[128 * 32];
  __shared__ __align__(16) short Bs[128 * 32];

  const int tid = threadIdx.x;
  const int lane = tid & 63;
  const int wv = tid >> 6;
  const int col = lane & 15, quad = lane >> 4;
  const int wr = wv >> 1, wc = wv & 1;
  const int bm = blockIdx.x >> 3;
  const int bn = blockIdx.x & 7;

  const int srow = wv * 16 + (lane >> 2);
  const int skoff = (lane & 3) * 8;
  const short* gA0 = att + (size_t)(bm * 128 + srow) * D_MODEL + skoff;
  const short* gA1 = gA0 + (size_t)64 * D_MODEL;
  const short* gB0 = Wob + (size_t)(bn * 128 + srow) * D_MODEL + skoff;
  const short* gB1 = gB0 + (size_t)64 * D_MODEL;
  short* lA0 = As + (wv * 16) * 32;
  short* lA1 = lA0 + 64 * 32;
  short* lB0 = Bs + (wv * 16) * 32;
  short* lB1 = lB0 + 64 * 32;

  floatx4 acc[4][4];
#pragma unroll
  for (int i = 0; i < 4; ++i)
#pragma unroll
    for (int j = 0; j < 4; ++j) acc[i][j] = (floatx4){0.f, 0.f, 0.f, 0.f};

  for (int k0 = 0; k0 < D_MODEL; k0 += 32) {
    __syncthreads();
    gl2lds16(gA0 + k0, lA0);
    gl2lds16(gA1 + k0, lA1);
    gl2lds16(gB0 + k0, lB0);
    gl2lds16(gB1 + k0, lB1);
    __syncthreads();
    bf16x8 a[4], b[4];
#pragma unroll
    for (int mt = 0; mt < 4; ++mt)
      a[mt] = ld_frag(&As[(wr * 64 + mt * 16 + col) * 32 + quad * 8]);
#pragma unroll
    for (int nt = 0; nt < 4; ++nt)
      b[nt] = ld_frag(&Bs[(wc * 64 + nt * 16 + col) * 32 + quad * 8]);
#pragma unroll
    for (int mt = 0; mt < 4; ++mt)
#pragma unroll
      for (int nt = 0; nt < 4; ++nt)
        acc[mt][nt] = MFMA16(a[mt], b[nt], acc[mt][nt]);
  }

  const int tm = bm * 2 + wr;
  const int tn = bn * 2 + wc;
#pragma unroll
  for (int mt = 0; mt < 4; ++mt)
#pragma unroll
    for (int nt = 0; nt < 4; ++nt) {
      int n = tn * 64 + nt * 16 + col;
#pragma unroll
      for (int r = 0; r < 4; ++r) {
        int m = tm * 64 + mt * 16 + quad * 4 + r;
        out[(size_t)m * D_MODEL + n] = acc[mt][nt][r];
      }
    }
}

// ---------------------------------------------------------------------------
extern "C" void kernel_launch(void* const* d_in, const int* in_sizes, int n_in,
                              void* d_out, int out_size, void* d_ws, size_t ws_size,
                              hipStream_t stream) {
  const float* x  = (const float*)d_in[0];
  const float* Wq = (const float*)d_in[2];
  const float* Wk = (const float*)d_in[3];
  const float* Wv = (const float*)d_in[4];
  const float* Wo = (const float*)d_in[5];
  float* out = (float*)d_out;

  const size_t TENS = (size_t)NTOK * D_MODEL;
  const size_t WELEM = (size_t)D_MODEL * D_MODEL;

  short* qws  = (short*)d_out;
  short* xb   = (short*)d_out + TENS;
  short* kws  = (short*)d_ws;
  short* vtws = kws + TENS;
  short* attws = vtws + TENS;
  short* wqb = attws;
  short* wkb = wqb + WELEM;
  short* wvb = wkb + WELEM;
  float2* ropetab = (float2*)(wvb + WELEM);
  short* wob = kws;

  rope_tab_kernel<<<dim3(256), 256, 0, stream>>>(ropetab);
  cvt4_kernel<<<dim3(256, 4), 256, 0, stream>>>(x, Wq, Wk, Wv, xb, wqb, wkb, wvb);
  qkv_rope_kernel<<<dim3(256, 3), 256, 0, stream>>>(xb, wqb, wkb, wvb, ropetab, qws, kws, vtws);
  attn_kernel<<<dim3(2048), 256, 0, stream>>>(qws, kws, vtws, attws);
  cvt1_kernel<<<dim3(256), 256, 0, stream>>>(Wo, wob, (int)(WELEM >> 2));
  out_gemm_kernel<<<dim3(256), 256, 0, stream>>>(attws, wob, out);
}